// Round 15
// baseline (68.687 us; speedup 1.0000x reference)
//
#include <hip/hip_runtime.h>

#define NHEADS 4
#define HDIM   64
#define BATCH  8
#define SEQ    1024
#define CH     256   // H*hd = in_dim = out_dim
#define LOG2E  1.4426950408889634f
#define MC     128           // m-chunk per staging step
#define NC     (SEQ / MC)    // 8 chunks
#define LDP    132           // LDS row stride in floats

typedef float  f32x4  __attribute__((ext_vector_type(4)));
typedef __bf16 bf16x8 __attribute__((ext_vector_type(8)));
typedef short  s16x8  __attribute__((ext_vector_type(8)));
union FU { s16x8 s; bf16x8 b; };

__device__ inline unsigned short f2bf(float f) {
    unsigned u = __float_as_uint(f);
    return (unsigned short)((u + 0x7fffu + ((u >> 16) & 1u)) >> 16);
}
// nt accessors via ext_vector_type (builtin rejects HIP_vector_type float4)
__device__ inline float4 nt_load4(const float* p) {
    f32x4 v = __builtin_nontemporal_load(reinterpret_cast<const f32x4*>(p));
    return make_float4(v.x, v.y, v.z, v.w);
}
__device__ inline void nt_store4(float* p, float4 v) {
    f32x4 u = {v.x, v.y, v.z, v.w};
    __builtin_nontemporal_store(u, reinterpret_cast<f32x4*>(p));
}

// ---------------------------------------------------------------------------
// K0: WpT[ch][k] = bf16(Wp[k][ch])
// ---------------------------------------------------------------------------
__global__ __launch_bounds__(256) void wpt_cast(const float* __restrict__ Wp,
                                                unsigned short* __restrict__ WpT) {
    __shared__ float T[32][33];
    const int t = threadIdx.x;
    const int kt = blockIdx.x * 32, ct = blockIdx.y * 32;
    const int r = t >> 3, c4 = (t & 7) * 4;
    float4 v = *reinterpret_cast<const float4*>(&Wp[(size_t)(kt + r) * CH + ct + c4]);
    T[r][c4 + 0] = v.x; T[r][c4 + 1] = v.y; T[r][c4 + 2] = v.z; T[r][c4 + 3] = v.w;
    __syncthreads();
    unsigned p0 = (unsigned)f2bf(T[c4 + 0][r]) | ((unsigned)f2bf(T[c4 + 1][r]) << 16);
    unsigned p1 = (unsigned)f2bf(T[c4 + 2][r]) | ((unsigned)f2bf(T[c4 + 3][r]) << 16);
    uint2 o = make_uint2(p0, p1);
    *reinterpret_cast<uint2*>(&WpT[(size_t)(ct + r) * CH + kt + c4]) = o;
}

// ---------------------------------------------------------------------------
// K1: projT = (x @ Wp)^T via MFMA, x HBM loads hoisted (R13, kept: -5us).
// ---------------------------------------------------------------------------
__global__ __launch_bounds__(256, 2) void proj_fused(const float* __restrict__ x,
                                                     const unsigned short* __restrict__ WpT,
                                                     const float* __restrict__ Ws,
                                                     unsigned short* __restrict__ projT,
                                                     float* __restrict__ sl,
                                                     float* __restrict__ sr) {
    const int t = threadIdx.x, w = t >> 6, l = t & 63, il = l & 15, g = l >> 4;
    const int row0 = blockIdx.x * 16;
    const int b = row0 >> 10, n0 = row0 & 1023;

    const unsigned short* Ap = WpT + (size_t)(w * 64 + il) * CH + g * 8;
    const float*          Bp = x + (size_t)(row0 + il) * CH + g * 8;

    float4 xv[8][2];
#pragma unroll
    for (int kt = 0; kt < 8; ++kt) {
        xv[kt][0] = *reinterpret_cast<const float4*>(Bp + kt * 32);
        xv[kt][1] = *reinterpret_cast<const float4*>(Bp + kt * 32 + 4);
    }

    f32x4 acc[4] = {};
#pragma unroll
    for (int kt = 0; kt < 8; ++kt) {
        FU a[4], bb;
#pragma unroll
        for (int ai = 0; ai < 4; ++ai)
            a[ai].s = *reinterpret_cast<const s16x8*>(Ap + (size_t)ai * 16 * CH + kt * 32);
        bb.b[0] = (__bf16)xv[kt][0].x; bb.b[1] = (__bf16)xv[kt][0].y;
        bb.b[2] = (__bf16)xv[kt][0].z; bb.b[3] = (__bf16)xv[kt][0].w;
        bb.b[4] = (__bf16)xv[kt][1].x; bb.b[5] = (__bf16)xv[kt][1].y;
        bb.b[6] = (__bf16)xv[kt][1].z; bb.b[7] = (__bf16)xv[kt][1].w;
#pragma unroll
        for (int ai = 0; ai < 4; ++ai)
            acc[ai] = __builtin_amdgcn_mfma_f32_16x16x32_bf16(a[ai].b, bb.b, acc[ai], 0, 0, 0);
    }

    unsigned short* pTb = projT + ((size_t)(b * NHEADS + w) * HDIM) * SEQ + n0 + il;
#pragma unroll
    for (int ai = 0; ai < 4; ++ai)
#pragma unroll
        for (int q = 0; q < 4; ++q)
            pTb[(size_t)(ai * 16 + g * 4 + q) * SEQ] = f2bf(acc[ai][q]);

    float pl = 0.f, pr = 0.f;
#pragma unroll
    for (int ai = 0; ai < 4; ++ai) {
        float4 wlv = *reinterpret_cast<const float4*>(&Ws[ai * 16 + g * 4]);
        float4 wrv = *reinterpret_cast<const float4*>(&Ws[HDIM + ai * 16 + g * 4]);
        pl += acc[ai][0] * wlv.x + acc[ai][1] * wlv.y + acc[ai][2] * wlv.z + acc[ai][3] * wlv.w;
        pr += acc[ai][0] * wrv.x + acc[ai][1] * wrv.y + acc[ai][2] * wrv.z + acc[ai][3] * wrv.w;
    }
    pl += __shfl_xor(pl, 16); pl += __shfl_xor(pl, 32);
    pr += __shfl_xor(pr, 16); pr += __shfl_xor(pr, 32);
    if (l < 16) {
        sl[(size_t)(b * NHEADS + w) * SEQ + n0 + il] = pl * LOG2E;
        sr[(size_t)(b * NHEADS + w) * SEQ + n0 + il] = pr * LOG2E;
    }
}

// ---------------------------------------------------------------------------
// K3: attention v11 = R13 attn10 + NON-TEMPORAL stream hygiene:
//     adj loads nt (read-once, no L2 allocate), out_adj/out stores nt (no
//     write-allocate). projT/sr keep normal caching -> stay L2-resident
//     instead of being washed out by the 8MB/XCD adj+copy streams.
// ---------------------------------------------------------------------------
template <bool FUSE_ADJ>
__global__ __launch_bounds__(256, 2) void attn11(const float* __restrict__ x,
                                                 const float* __restrict__ adj,
                                                 const unsigned short* __restrict__ projT,
                                                 const float* __restrict__ sl,
                                                 const float* __restrict__ sr,
                                                 const float* __restrict__ Ws,
                                                 const float* __restrict__ bias,
                                                 float* __restrict__ out,
                                                 float* __restrict__ out_adj) {
    __shared__ __align__(16) float abuf[2][16][LDP];

    const int t = threadIdx.x;
    const int h = t >> 6, l = t & 63, il = l & 15, g = l >> 4;
    const int b  = blockIdx.x & 7;        // XCD-aligned batch
    const int i0 = (blockIdx.x >> 3) * 16;
    const float wa2 = Ws[2 * HDIM] * LOG2E;

    const int str = t >> 4;
    const int stc = (t & 15) * 4;
    const size_t astg = ((size_t)(b * SEQ + i0 + str)) * SEQ + stc;

    const float sl_i = sl[(size_t)(b * NHEADS + h) * SEQ + i0 + il];
    const float* srp = sr + (size_t)(b * NHEADS + h) * SEQ;
    const unsigned short* pT = projT + ((size_t)(b * NHEADS + h) * HDIM + il) * SEQ + g * 8;

    FU ones;
#pragma unroll
    for (int j = 0; j < 8; ++j) ones.s[j] = (short)0x3F80;

    f32x4 acc[4] = {};
    f32x4 dacc = {};

    float4 c00 = nt_load4(adj + astg);
    float4 c01 = nt_load4(adj + astg + 64);
    float4 cur0 = nt_load4(adj + astg + MC);
    float4 cur1 = nt_load4(adj + astg + MC + 64);
    if (FUSE_ADJ) {
        nt_store4(out_adj + astg, c00);
        nt_store4(out_adj + astg + 64, c01);
    }
    *reinterpret_cast<float4*>(&abuf[0][str][stc])      = c00;
    *reinterpret_cast<float4*>(&abuf[0][str][stc + 64]) = c01;
    __syncthreads();

    for (int c = 0; c < NC; ++c) {
        // (1) issue next-next staging loads (nt)
        float4 nx0 = {}, nx1 = {};
        if (c + 2 < NC) {
            nx0 = nt_load4(adj + astg + (size_t)(c + 2) * MC);
            nx1 = nt_load4(adj + astg + (size_t)(c + 2) * MC + 64);
        }
        const float* aT = &abuf[c & 1][il][0];
        const int mt = c * MC;

        // (2) batch-load chunk operands
        float4 av[4][2], sv4[4][2];
        FU B[4][4];
#pragma unroll
        for (int kq = 0; kq < 4; ++kq) {
            const int mk = kq * 32 + g * 8;
            av[kq][0]  = *reinterpret_cast<const float4*>(aT + mk);
            av[kq][1]  = *reinterpret_cast<const float4*>(aT + mk + 4);
            sv4[kq][0] = *reinterpret_cast<const float4*>(srp + mt + mk);
            sv4[kq][1] = *reinterpret_cast<const float4*>(srp + mt + mk + 4);
        }
#pragma unroll
        for (int kq = 0; kq < 4; ++kq) {
#pragma unroll
            for (int bj = 0; bj < 4; ++bj)
                B[kq][bj].s = *reinterpret_cast<const s16x8*>(pT + mt + kq * 32 + (size_t)(bj * 16) * SEQ);
        }

        // (3) e-chains
        FU af[4];
#pragma unroll
        for (int kq = 0; kq < 4; ++kq) {
            float aj[8] = {av[kq][0].x, av[kq][0].y, av[kq][0].z, av[kq][0].w,
                           av[kq][1].x, av[kq][1].y, av[kq][1].z, av[kq][1].w};
            float sv[8] = {sv4[kq][0].x, sv4[kq][0].y, sv4[kq][0].z, sv4[kq][0].w,
                           sv4[kq][1].x, sv4[kq][1].y, sv4[kq][1].z, sv4[kq][1].w};
#pragma unroll
            for (int j = 0; j < 8; ++j) {
                float s = fmaf(aj[j], wa2, sl_i + sv[j]);
                s = __builtin_amdgcn_fmed3f(s, 0.2f * s, 86.5617f);
                float e = (aj[j] <= 1e-5f) ? 0.f : __builtin_amdgcn_exp2f(s);
                af[kq].b[j] = (__bf16)e;
            }
        }

        // (4) MFMAs
#pragma unroll
        for (int kq = 0; kq < 4; ++kq) {
            acc[0] = __builtin_amdgcn_mfma_f32_16x16x32_bf16(af[kq].b, B[kq][0].b, acc[0], 0, 0, 0);
            acc[1] = __builtin_amdgcn_mfma_f32_16x16x32_bf16(af[kq].b, B[kq][1].b, acc[1], 0, 0, 0);
            acc[2] = __builtin_amdgcn_mfma_f32_16x16x32_bf16(af[kq].b, B[kq][2].b, acc[2], 0, 0, 0);
            acc[3] = __builtin_amdgcn_mfma_f32_16x16x32_bf16(af[kq].b, B[kq][3].b, acc[3], 0, 0, 0);
            dacc   = __builtin_amdgcn_mfma_f32_16x16x32_bf16(af[kq].b, ones.b,   dacc,   0, 0, 0);
        }

        // (5) stage c+1 + nt copy write
        if (c + 1 < NC) {
            if (FUSE_ADJ) {
                nt_store4(out_adj + astg + (size_t)(c + 1) * MC, cur0);
                nt_store4(out_adj + astg + (size_t)(c + 1) * MC + 64, cur1);
            }
            *reinterpret_cast<float4*>(&abuf[(c + 1) & 1][str][stc])      = cur0;
            *reinterpret_cast<float4*>(&abuf[(c + 1) & 1][str][stc + 64]) = cur1;
        }
        __syncthreads();
        cur0 = nx0; cur1 = nx1;
    }

    const float* bb = bias + h * HDIM;
#pragma unroll
    for (int q = 0; q < 4; ++q) {
        const float inv = 1.f / dacc[q];
        const size_t ob = ((size_t)(b * SEQ + i0 + g * 4 + q)) * CH + h * HDIM + il;
#pragma unroll
        for (int bj = 0; bj < 4; ++bj) {
            float v = fmaf(acc[bj][q], inv, x[ob + bj * 16] + bb[bj * 16 + il]);
            v = fmaxf(v, 0.5f * v);
            __builtin_nontemporal_store(v, out + ob + bj * 16);
        }
    }
}

// ---------------------------------------------------------------------------
// K4 (fallback): copy adj into output chunk 2
// ---------------------------------------------------------------------------
__global__ void adjcopy(const float* __restrict__ adj, float* __restrict__ dst, int n4) {
    int idx = blockIdx.x * blockDim.x + threadIdx.x;
    int stride = gridDim.x * blockDim.x;
    const float4* s = reinterpret_cast<const float4*>(adj);
    float4* d = reinterpret_cast<float4*>(dst);
    for (int i = idx; i < n4; i += stride) d[i] = s[i];
}

extern "C" void kernel_launch(void* const* d_in, const int* in_sizes, int n_in,
                              void* d_out, int out_size, void* d_ws, size_t ws_size,
                              hipStream_t stream) {
    const float* x    = (const float*)d_in[0];
    const float* adj  = (const float*)d_in[1];
    const float* Wp   = (const float*)d_in[2];
    const float* Ws   = (const float*)d_in[3];
    const float* bias = (const float*)d_in[4];
    float* out     = (float*)d_out;
    float* out_adj = out + (size_t)BATCH * SEQ * CH;

    const size_t nProj = (size_t)BATCH * SEQ * CH;
    const size_t nSc   = (size_t)BATCH * NHEADS * SEQ;
    const size_t need  = CH * CH * 2 + nProj * 2 + 2 * nSc * 4;
    const bool use_ws  = (ws_size >= need);
    char* scratch = use_ws ? (char*)d_ws : (char*)out_adj;
    unsigned short* WpT   = (unsigned short*)scratch;
    unsigned short* projT = (unsigned short*)(scratch + (size_t)CH * CH * 2);
    float*          sl    = (float*)(scratch + (size_t)CH * CH * 2 + nProj * 2);
    float*          sr    = sl + nSc;

    wpt_cast<<<dim3(8, 8), 256, 0, stream>>>(Wp, WpT);
    proj_fused<<<dim3(512), 256, 0, stream>>>(x, WpT, Ws, projT, sl, sr);
    if (use_ws) {
        attn11<true><<<dim3(512), 256, 0, stream>>>(
            x, adj, projT, sl, sr, Ws, bias, out, out_adj);
    } else {
        attn11<false><<<dim3(512), 256, 0, stream>>>(
            x, adj, projT, sl, sr, Ws, bias, out, out_adj);
        adjcopy<<<2048, 256, 0, stream>>>(adj, out_adj, (BATCH * SEQ * SEQ) / 4);
    }
}

// Round 16
// 53.921 us; speedup vs baseline: 1.2738x; 1.2738x over previous
//
#include <hip/hip_runtime.h>

#define NHEADS 4
#define HDIM   64
#define BATCH  8
#define SEQ    1024
#define CH     256   // H*hd = in_dim = out_dim
#define LOG2E  1.4426950408889634f
#define MC     128           // m-chunk per staging step
#define NC     (SEQ / MC)    // 8 chunks
#define LDP    132           // LDS row stride in floats

typedef float  f32x4  __attribute__((ext_vector_type(4)));
typedef __bf16 bf16x8 __attribute__((ext_vector_type(8)));
typedef short  s16x8  __attribute__((ext_vector_type(8)));
union FU { s16x8 s; bf16x8 b; };

__device__ inline unsigned short f2bf(float f) {
    unsigned u = __float_as_uint(f);
    return (unsigned short)((u + 0x7fffu + ((u >> 16) & 1u)) >> 16);
}
__device__ inline float4 nt_load4(const float* p) {
    f32x4 v = __builtin_nontemporal_load(reinterpret_cast<const f32x4*>(p));
    return make_float4(v.x, v.y, v.z, v.w);
}
__device__ inline void nt_store4(float* p, float4 v) {
    f32x4 u = {v.x, v.y, v.z, v.w};
    __builtin_nontemporal_store(u, reinterpret_cast<f32x4*>(p));
}

// projT B-SWIZZLED layout, per (b,h): 65536 shorts (128KB).
// element (d, m) -> unit (mB=m>>4, dB=d>>4) of 256 shorts, inner
// [md=(m>>3)&1][dl=d&15][me=m&7]:
//   short_idx = ((mB*4 + dB)*256) + md*128 + dl*8 + me
// attn B-frag load (lane il,g; m-base M mult of 32; d-base bj*16):
//   addr = base_bh + (g>>1)*1024 + (g&1)*128 + il*8   [per-lane, contiguous]
//        + (M>>4)*1024 + bj*256                        [wave-uniform]
// -> each wave-load touches 2 contiguous 512B segments (was 16 x 64B).

// ---------------------------------------------------------------------------
// K0: WpT[ch][k] = bf16(Wp[k][ch])
// ---------------------------------------------------------------------------
__global__ __launch_bounds__(256) void wpt_cast(const float* __restrict__ Wp,
                                                unsigned short* __restrict__ WpT) {
    __shared__ float T[32][33];
    const int t = threadIdx.x;
    const int kt = blockIdx.x * 32, ct = blockIdx.y * 32;
    const int r = t >> 3, c4 = (t & 7) * 4;
    float4 v = *reinterpret_cast<const float4*>(&Wp[(size_t)(kt + r) * CH + ct + c4]);
    T[r][c4 + 0] = v.x; T[r][c4 + 1] = v.y; T[r][c4 + 2] = v.z; T[r][c4 + 3] = v.w;
    __syncthreads();
    unsigned p0 = (unsigned)f2bf(T[c4 + 0][r]) | ((unsigned)f2bf(T[c4 + 1][r]) << 16);
    unsigned p1 = (unsigned)f2bf(T[c4 + 2][r]) | ((unsigned)f2bf(T[c4 + 3][r]) << 16);
    uint2 o = make_uint2(p0, p1);
    *reinterpret_cast<uint2*>(&WpT[(size_t)(ct + r) * CH + kt + c4]) = o;
}

// ---------------------------------------------------------------------------
// K1: projT(B-swizzled) = (x @ Wp)^T via MFMA; x HBM loads hoisted.
//     acc[ai][q] = proj[ch=w*64+ai*16+g*4+q][m=n0+il] -> swizzled scatter:
//     all 16 stores land within one 512B unit region (was 32KB span).
// ---------------------------------------------------------------------------
__global__ __launch_bounds__(256, 2) void proj_fused(const float* __restrict__ x,
                                                     const unsigned short* __restrict__ WpT,
                                                     const float* __restrict__ Ws,
                                                     unsigned short* __restrict__ projT,
                                                     float* __restrict__ sl,
                                                     float* __restrict__ sr) {
    const int t = threadIdx.x, w = t >> 6, l = t & 63, il = l & 15, g = l >> 4;
    const int row0 = blockIdx.x * 16;
    const int b = row0 >> 10, n0 = row0 & 1023;

    const unsigned short* Ap = WpT + (size_t)(w * 64 + il) * CH + g * 8;
    const float*          Bp = x + (size_t)(row0 + il) * CH + g * 8;

    float4 xv[8][2];
#pragma unroll
    for (int kt = 0; kt < 8; ++kt) {
        xv[kt][0] = *reinterpret_cast<const float4*>(Bp + kt * 32);
        xv[kt][1] = *reinterpret_cast<const float4*>(Bp + kt * 32 + 4);
    }

    f32x4 acc[4] = {};
#pragma unroll
    for (int kt = 0; kt < 8; ++kt) {
        FU a[4], bb;
#pragma unroll
        for (int ai = 0; ai < 4; ++ai)
            a[ai].s = *reinterpret_cast<const s16x8*>(Ap + (size_t)ai * 16 * CH + kt * 32);
        bb.b[0] = (__bf16)xv[kt][0].x; bb.b[1] = (__bf16)xv[kt][0].y;
        bb.b[2] = (__bf16)xv[kt][0].z; bb.b[3] = (__bf16)xv[kt][0].w;
        bb.b[4] = (__bf16)xv[kt][1].x; bb.b[5] = (__bf16)xv[kt][1].y;
        bb.b[6] = (__bf16)xv[kt][1].z; bb.b[7] = (__bf16)xv[kt][1].w;
#pragma unroll
        for (int ai = 0; ai < 4; ++ai)
            acc[ai] = __builtin_amdgcn_mfma_f32_16x16x32_bf16(a[ai].b, bb.b, acc[ai], 0, 0, 0);
    }

    // swizzled store: d = ai*16 + g*4 + q, m = n0 + il
    unsigned short* pS = projT + (((size_t)(b * NHEADS + w)) << 16)
                       + (size_t)(n0 >> 4) * 1024 + (il >> 3) * 128 + (il & 7);
#pragma unroll
    for (int ai = 0; ai < 4; ++ai)
#pragma unroll
        for (int q = 0; q < 4; ++q)
            pS[ai * 256 + (g * 4 + q) * 8] = f2bf(acc[ai][q]);

    float pl = 0.f, pr = 0.f;
#pragma unroll
    for (int ai = 0; ai < 4; ++ai) {
        float4 wlv = *reinterpret_cast<const float4*>(&Ws[ai * 16 + g * 4]);
        float4 wrv = *reinterpret_cast<const float4*>(&Ws[HDIM + ai * 16 + g * 4]);
        pl += acc[ai][0] * wlv.x + acc[ai][1] * wlv.y + acc[ai][2] * wlv.z + acc[ai][3] * wlv.w;
        pr += acc[ai][0] * wrv.x + acc[ai][1] * wrv.y + acc[ai][2] * wrv.z + acc[ai][3] * wrv.w;
    }
    pl += __shfl_xor(pl, 16); pl += __shfl_xor(pl, 32);
    pr += __shfl_xor(pr, 16); pr += __shfl_xor(pr, 32);
    if (l < 16) {
        sl[(size_t)(b * NHEADS + w) * SEQ + n0 + il] = pl * LOG2E;
        sr[(size_t)(b * NHEADS + w) * SEQ + n0 + il] = pr * LOG2E;
    }
}

// ---------------------------------------------------------------------------
// K3: attention v12 = attn11 + B-swizzled projT loads (2 segments per load
//     instead of 16). XCD batch mapping, adj LDS staging + fused nt copy kept.
// ---------------------------------------------------------------------------
template <bool FUSE_ADJ>
__global__ __launch_bounds__(256, 2) void attn12(const float* __restrict__ x,
                                                 const float* __restrict__ adj,
                                                 const unsigned short* __restrict__ projT,
                                                 const float* __restrict__ sl,
                                                 const float* __restrict__ sr,
                                                 const float* __restrict__ Ws,
                                                 const float* __restrict__ bias,
                                                 float* __restrict__ out,
                                                 float* __restrict__ out_adj) {
    __shared__ __align__(16) float abuf[2][16][LDP];

    const int t = threadIdx.x;
    const int h = t >> 6, l = t & 63, il = l & 15, g = l >> 4;
    const int b  = blockIdx.x & 7;        // XCD-aligned batch
    const int i0 = (blockIdx.x >> 3) * 16;
    const float wa2 = Ws[2 * HDIM] * LOG2E;

    const int str = t >> 4;
    const int stc = (t & 15) * 4;
    const size_t astg = ((size_t)(b * SEQ + i0 + str)) * SEQ + stc;

    const float sl_i = sl[(size_t)(b * NHEADS + h) * SEQ + i0 + il];
    const float* srp = sr + (size_t)(b * NHEADS + h) * SEQ;
    // B-swizzled per-lane base (contiguous 16B per lane)
    const unsigned short* pTsw = projT + (((size_t)(b * NHEADS + h)) << 16)
                               + (g >> 1) * 1024 + (g & 1) * 128 + il * 8;

    FU ones;
#pragma unroll
    for (int j = 0; j < 8; ++j) ones.s[j] = (short)0x3F80;

    f32x4 acc[4] = {};
    f32x4 dacc = {};

    float4 c00 = nt_load4(adj + astg);
    float4 c01 = nt_load4(adj + astg + 64);
    float4 cur0 = nt_load4(adj + astg + MC);
    float4 cur1 = nt_load4(adj + astg + MC + 64);
    if (FUSE_ADJ) {
        nt_store4(out_adj + astg, c00);
        nt_store4(out_adj + astg + 64, c01);
    }
    *reinterpret_cast<float4*>(&abuf[0][str][stc])      = c00;
    *reinterpret_cast<float4*>(&abuf[0][str][stc + 64]) = c01;
    __syncthreads();

    for (int c = 0; c < NC; ++c) {
        // (1) issue next-next staging loads (nt)
        float4 nx0 = {}, nx1 = {};
        if (c + 2 < NC) {
            nx0 = nt_load4(adj + astg + (size_t)(c + 2) * MC);
            nx1 = nt_load4(adj + astg + (size_t)(c + 2) * MC + 64);
        }
        const float* aT = &abuf[c & 1][il][0];
        const int mt = c * MC;

        // (2) batch-load chunk operands
        float4 av[4][2], sv4[4][2];
        FU B[4][4];
#pragma unroll
        for (int kq = 0; kq < 4; ++kq) {
            const int mk = kq * 32 + g * 8;
            av[kq][0]  = *reinterpret_cast<const float4*>(aT + mk);
            av[kq][1]  = *reinterpret_cast<const float4*>(aT + mk + 4);
            sv4[kq][0] = *reinterpret_cast<const float4*>(srp + mt + mk);
            sv4[kq][1] = *reinterpret_cast<const float4*>(srp + mt + mk + 4);
        }
#pragma unroll
        for (int kq = 0; kq < 4; ++kq) {
#pragma unroll
            for (int bj = 0; bj < 4; ++bj)
                B[kq][bj].s = *reinterpret_cast<const s16x8*>(
                    pTsw + c * 8192 + kq * 2048 + bj * 256);
        }

        // (3) e-chains
        FU af[4];
#pragma unroll
        for (int kq = 0; kq < 4; ++kq) {
            float aj[8] = {av[kq][0].x, av[kq][0].y, av[kq][0].z, av[kq][0].w,
                           av[kq][1].x, av[kq][1].y, av[kq][1].z, av[kq][1].w};
            float sv[8] = {sv4[kq][0].x, sv4[kq][0].y, sv4[kq][0].z, sv4[kq][0].w,
                           sv4[kq][1].x, sv4[kq][1].y, sv4[kq][1].z, sv4[kq][1].w};
#pragma unroll
            for (int j = 0; j < 8; ++j) {
                float s = fmaf(aj[j], wa2, sl_i + sv[j]);
                s = __builtin_amdgcn_fmed3f(s, 0.2f * s, 86.5617f);
                float e = (aj[j] <= 1e-5f) ? 0.f : __builtin_amdgcn_exp2f(s);
                af[kq].b[j] = (__bf16)e;
            }
        }

        // (4) MFMAs
#pragma unroll
        for (int kq = 0; kq < 4; ++kq) {
            acc[0] = __builtin_amdgcn_mfma_f32_16x16x32_bf16(af[kq].b, B[kq][0].b, acc[0], 0, 0, 0);
            acc[1] = __builtin_amdgcn_mfma_f32_16x16x32_bf16(af[kq].b, B[kq][1].b, acc[1], 0, 0, 0);
            acc[2] = __builtin_amdgcn_mfma_f32_16x16x32_bf16(af[kq].b, B[kq][2].b, acc[2], 0, 0, 0);
            acc[3] = __builtin_amdgcn_mfma_f32_16x16x32_bf16(af[kq].b, B[kq][3].b, acc[3], 0, 0, 0);
            dacc   = __builtin_amdgcn_mfma_f32_16x16x32_bf16(af[kq].b, ones.b,   dacc,   0, 0, 0);
        }

        // (5) stage c+1 + nt copy write
        if (c + 1 < NC) {
            if (FUSE_ADJ) {
                nt_store4(out_adj + astg + (size_t)(c + 1) * MC, cur0);
                nt_store4(out_adj + astg + (size_t)(c + 1) * MC + 64, cur1);
            }
            *reinterpret_cast<float4*>(&abuf[(c + 1) & 1][str][stc])      = cur0;
            *reinterpret_cast<float4*>(&abuf[(c + 1) & 1][str][stc + 64]) = cur1;
        }
        __syncthreads();
        cur0 = nx0; cur1 = nx1;
    }

    const float* bb = bias + h * HDIM;
#pragma unroll
    for (int q = 0; q < 4; ++q) {
        const float inv = 1.f / dacc[q];
        const size_t ob = ((size_t)(b * SEQ + i0 + g * 4 + q)) * CH + h * HDIM + il;
#pragma unroll
        for (int bj = 0; bj < 4; ++bj) {
            float v = fmaf(acc[bj][q], inv, x[ob + bj * 16] + bb[bj * 16 + il]);
            v = fmaxf(v, 0.5f * v);
            __builtin_nontemporal_store(v, out + ob + bj * 16);
        }
    }
}

// ---------------------------------------------------------------------------
// K4 (fallback): copy adj into output chunk 2
// ---------------------------------------------------------------------------
__global__ void adjcopy(const float* __restrict__ adj, float* __restrict__ dst, int n4) {
    int idx = blockIdx.x * blockDim.x + threadIdx.x;
    int stride = gridDim.x * blockDim.x;
    const float4* s = reinterpret_cast<const float4*>(adj);
    float4* d = reinterpret_cast<float4*>(dst);
    for (int i = idx; i < n4; i += stride) d[i] = s[i];
}

extern "C" void kernel_launch(void* const* d_in, const int* in_sizes, int n_in,
                              void* d_out, int out_size, void* d_ws, size_t ws_size,
                              hipStream_t stream) {
    const float* x    = (const float*)d_in[0];
    const float* adj  = (const float*)d_in[1];
    const float* Wp   = (const float*)d_in[2];
    const float* Ws   = (const float*)d_in[3];
    const float* bias = (const float*)d_in[4];
    float* out     = (float*)d_out;
    float* out_adj = out + (size_t)BATCH * SEQ * CH;

    const size_t nProj = (size_t)BATCH * SEQ * CH;
    const size_t nSc   = (size_t)BATCH * NHEADS * SEQ;
    const size_t need  = CH * CH * 2 + nProj * 2 + 2 * nSc * 4;
    const bool use_ws  = (ws_size >= need);
    char* scratch = use_ws ? (char*)d_ws : (char*)out_adj;
    unsigned short* WpT   = (unsigned short*)scratch;
    unsigned short* projT = (unsigned short*)(scratch + (size_t)CH * CH * 2);
    float*          sl    = (float*)(scratch + (size_t)CH * CH * 2 + nProj * 2);
    float*          sr    = sl + nSc;

    wpt_cast<<<dim3(8, 8), 256, 0, stream>>>(Wp, WpT);
    proj_fused<<<dim3(512), 256, 0, stream>>>(x, WpT, Ws, projT, sl, sr);
    if (use_ws) {
        attn12<true><<<dim3(512), 256, 0, stream>>>(
            x, adj, projT, sl, sr, Ws, bias, out, out_adj);
    } else {
        attn12<false><<<dim3(512), 256, 0, stream>>>(
            x, adj, projT, sl, sr, Ws, bias, out, out_adj);
        adjcopy<<<2048, 256, 0, stream>>>(adj, out_adj, (BATCH * SEQ * SEQ) / 4);
    }
}

// Round 17
// 51.152 us; speedup vs baseline: 1.3428x; 1.0541x over previous
//
#include <hip/hip_runtime.h>

#define NHEADS 4
#define HDIM   64
#define BATCH  8
#define SEQ    1024
#define CH     256   // H*hd = in_dim = out_dim
#define LOG2E  1.4426950408889634f
#define MC     128           // m-chunk per staging step
#define LDP    132           // LDS row stride in floats

typedef float  f32x4  __attribute__((ext_vector_type(4)));
typedef __bf16 bf16x8 __attribute__((ext_vector_type(8)));
typedef short  s16x8  __attribute__((ext_vector_type(8)));
union FU { s16x8 s; bf16x8 b; };

__device__ inline unsigned short f2bf(float f) {
    unsigned u = __float_as_uint(f);
    return (unsigned short)((u + 0x7fffu + ((u >> 16) & 1u)) >> 16);
}
__device__ inline float4 nt_load4(const float* p) {
    f32x4 v = __builtin_nontemporal_load(reinterpret_cast<const f32x4*>(p));
    return make_float4(v.x, v.y, v.z, v.w);
}
__device__ inline void nt_store4(float* p, float4 v) {
    f32x4 u = {v.x, v.y, v.z, v.w};
    __builtin_nontemporal_store(u, reinterpret_cast<f32x4*>(p));
}

// projT B-SWIZZLED layout, per (b,h): 65536 shorts (128KB).
// (d,m) -> short_idx = ((m>>4)*4 + (d>>4))*256 + ((m>>3)&1)*128 + (d&15)*8 + (m&7)
// attn B-load: per-lane contiguous 16B, wave-uniform chunk offset ->
// 2 contiguous 512B segments per wave-load (was 16 x 64B).

// ---------------------------------------------------------------------------
// K0: WpT[ch][k] = bf16(Wp[k][ch])
// ---------------------------------------------------------------------------
__global__ __launch_bounds__(256) void wpt_cast(const float* __restrict__ Wp,
                                                unsigned short* __restrict__ WpT) {
    __shared__ float T[32][33];
    const int t = threadIdx.x;
    const int kt = blockIdx.x * 32, ct = blockIdx.y * 32;
    const int r = t >> 3, c4 = (t & 7) * 4;
    float4 v = *reinterpret_cast<const float4*>(&Wp[(size_t)(kt + r) * CH + ct + c4]);
    T[r][c4 + 0] = v.x; T[r][c4 + 1] = v.y; T[r][c4 + 2] = v.z; T[r][c4 + 3] = v.w;
    __syncthreads();
    unsigned p0 = (unsigned)f2bf(T[c4 + 0][r]) | ((unsigned)f2bf(T[c4 + 1][r]) << 16);
    unsigned p1 = (unsigned)f2bf(T[c4 + 2][r]) | ((unsigned)f2bf(T[c4 + 3][r]) << 16);
    uint2 o = make_uint2(p0, p1);
    *reinterpret_cast<uint2*>(&WpT[(size_t)(ct + r) * CH + kt + c4]) = o;
}

// ---------------------------------------------------------------------------
// K1: projT(B-swizzled) = (x @ Wp)^T via MFMA; x HBM loads hoisted.
// ---------------------------------------------------------------------------
__global__ __launch_bounds__(256, 2) void proj_fused(const float* __restrict__ x,
                                                     const unsigned short* __restrict__ WpT,
                                                     const float* __restrict__ Ws,
                                                     unsigned short* __restrict__ projT,
                                                     float* __restrict__ sl,
                                                     float* __restrict__ sr) {
    const int t = threadIdx.x, w = t >> 6, l = t & 63, il = l & 15, g = l >> 4;
    const int row0 = blockIdx.x * 16;
    const int b = row0 >> 10, n0 = row0 & 1023;

    const unsigned short* Ap = WpT + (size_t)(w * 64 + il) * CH + g * 8;
    const float*          Bp = x + (size_t)(row0 + il) * CH + g * 8;

    float4 xv[8][2];
#pragma unroll
    for (int kt = 0; kt < 8; ++kt) {
        xv[kt][0] = *reinterpret_cast<const float4*>(Bp + kt * 32);
        xv[kt][1] = *reinterpret_cast<const float4*>(Bp + kt * 32 + 4);
    }

    f32x4 acc[4] = {};
#pragma unroll
    for (int kt = 0; kt < 8; ++kt) {
        FU a[4], bb;
#pragma unroll
        for (int ai = 0; ai < 4; ++ai)
            a[ai].s = *reinterpret_cast<const s16x8*>(Ap + (size_t)ai * 16 * CH + kt * 32);
        bb.b[0] = (__bf16)xv[kt][0].x; bb.b[1] = (__bf16)xv[kt][0].y;
        bb.b[2] = (__bf16)xv[kt][0].z; bb.b[3] = (__bf16)xv[kt][0].w;
        bb.b[4] = (__bf16)xv[kt][1].x; bb.b[5] = (__bf16)xv[kt][1].y;
        bb.b[6] = (__bf16)xv[kt][1].z; bb.b[7] = (__bf16)xv[kt][1].w;
#pragma unroll
        for (int ai = 0; ai < 4; ++ai)
            acc[ai] = __builtin_amdgcn_mfma_f32_16x16x32_bf16(a[ai].b, bb.b, acc[ai], 0, 0, 0);
    }

    unsigned short* pS = projT + (((size_t)(b * NHEADS + w)) << 16)
                       + (size_t)(n0 >> 4) * 1024 + (il >> 3) * 128 + (il & 7);
#pragma unroll
    for (int ai = 0; ai < 4; ++ai)
#pragma unroll
        for (int q = 0; q < 4; ++q)
            pS[ai * 256 + (g * 4 + q) * 8] = f2bf(acc[ai][q]);

    float pl = 0.f, pr = 0.f;
#pragma unroll
    for (int ai = 0; ai < 4; ++ai) {
        float4 wlv = *reinterpret_cast<const float4*>(&Ws[ai * 16 + g * 4]);
        float4 wrv = *reinterpret_cast<const float4*>(&Ws[HDIM + ai * 16 + g * 4]);
        pl += acc[ai][0] * wlv.x + acc[ai][1] * wlv.y + acc[ai][2] * wlv.z + acc[ai][3] * wlv.w;
        pr += acc[ai][0] * wrv.x + acc[ai][1] * wrv.y + acc[ai][2] * wrv.z + acc[ai][3] * wrv.w;
    }
    pl += __shfl_xor(pl, 16); pl += __shfl_xor(pl, 32);
    pr += __shfl_xor(pr, 16); pr += __shfl_xor(pr, 32);
    if (l < 16) {
        sl[(size_t)(b * NHEADS + w) * SEQ + n0 + il] = pl * LOG2E;
        sr[(size_t)(b * NHEADS + w) * SEQ + n0 + il] = pr * LOG2E;
    }
}

// ---------------------------------------------------------------------------
// K3: attention v13 = attn12 body + 8 waves/block (512 thr): wave (h=w&3,
//     mh=w>>2); m split in halves (4 chunks of 128 each). 16 waves/CU.
//     LDS: dbuf x 2 halves x [16][LDP] (67.6KB). Cross-half combine overlays
//     LDS after final barrier. XCD batch mapping, B-swizzle, nt streams kept.
// ---------------------------------------------------------------------------
template <bool FUSE_ADJ>
__global__ __launch_bounds__(512, 2) void attn13(const float* __restrict__ x,
                                                 const float* __restrict__ adj,
                                                 const unsigned short* __restrict__ projT,
                                                 const float* __restrict__ sl,
                                                 const float* __restrict__ sr,
                                                 const float* __restrict__ Ws,
                                                 const float* __restrict__ bias,
                                                 float* __restrict__ out,
                                                 float* __restrict__ out_adj) {
    __shared__ __align__(16) float abuf[2][2][16][LDP];   // [dbuf][mh][row][col]

    const int t = threadIdx.x;
    const int w = t >> 6, l = t & 63, il = l & 15, g = l >> 4;
    const int h = w & 3, mh = w >> 2;
    const int b  = blockIdx.x & 7;        // XCD-aligned batch
    const int i0 = (blockIdx.x >> 3) * 16;
    const float wa2 = Ws[2 * HDIM] * LOG2E;

    // staging: thread t -> half = t>>8, row = (t>>4)&15, col = (t&15)*4 (+0/+64)
    const int sh = t >> 8;
    const int str = (t >> 4) & 15;
    const int stc = (t & 15) * 4;
    const size_t astg = ((size_t)(b * SEQ + i0 + str)) * SEQ + sh * 512 + stc;

    const float sl_i = sl[(size_t)(b * NHEADS + h) * SEQ + i0 + il];
    const float* srp = sr + (size_t)(b * NHEADS + h) * SEQ + mh * 512;
    // B-swizzled per-lane base for this wave's m-half
    const unsigned short* pTsw = projT + (((size_t)(b * NHEADS + h)) << 16)
                               + (size_t)mh * 32768
                               + (g >> 1) * 1024 + (g & 1) * 128 + il * 8;

    FU ones;
#pragma unroll
    for (int j = 0; j < 8; ++j) ones.s[j] = (short)0x3F80;

    f32x4 acc[4] = {};
    f32x4 dacc = {};

    // prologue: stage chunk 0 of both halves; prefetch chunk 1
    float4 c00 = nt_load4(adj + astg);
    float4 c01 = nt_load4(adj + astg + 64);
    float4 cur0 = nt_load4(adj + astg + MC);
    float4 cur1 = nt_load4(adj + astg + MC + 64);
    if (FUSE_ADJ) {
        nt_store4(out_adj + astg, c00);
        nt_store4(out_adj + astg + 64, c01);
    }
    *reinterpret_cast<float4*>(&abuf[0][sh][str][stc])      = c00;
    *reinterpret_cast<float4*>(&abuf[0][sh][str][stc + 64]) = c01;
    __syncthreads();

    for (int c = 0; c < 4; ++c) {
        // (1) issue next-next staging loads (nt)
        float4 nx0 = {}, nx1 = {};
        if (c + 2 < 4) {
            nx0 = nt_load4(adj + astg + (size_t)(c + 2) * MC);
            nx1 = nt_load4(adj + astg + (size_t)(c + 2) * MC + 64);
        }
        const float* aT = &abuf[c & 1][mh][il][0];
        const int mt = c * MC;

        // (2) batch-load chunk operands
        float4 av[4][2], sv4[4][2];
        FU B[4][4];
#pragma unroll
        for (int kq = 0; kq < 4; ++kq) {
            const int mk = kq * 32 + g * 8;
            av[kq][0]  = *reinterpret_cast<const float4*>(aT + mk);
            av[kq][1]  = *reinterpret_cast<const float4*>(aT + mk + 4);
            sv4[kq][0] = *reinterpret_cast<const float4*>(srp + mt + mk);
            sv4[kq][1] = *reinterpret_cast<const float4*>(srp + mt + mk + 4);
        }
#pragma unroll
        for (int kq = 0; kq < 4; ++kq) {
#pragma unroll
            for (int bj = 0; bj < 4; ++bj)
                B[kq][bj].s = *reinterpret_cast<const s16x8*>(
                    pTsw + c * 8192 + kq * 2048 + bj * 256);
        }

        // (3) e-chains
        FU af[4];
#pragma unroll
        for (int kq = 0; kq < 4; ++kq) {
            float aj[8] = {av[kq][0].x, av[kq][0].y, av[kq][0].z, av[kq][0].w,
                           av[kq][1].x, av[kq][1].y, av[kq][1].z, av[kq][1].w};
            float sv[8] = {sv4[kq][0].x, sv4[kq][0].y, sv4[kq][0].z, sv4[kq][0].w,
                           sv4[kq][1].x, sv4[kq][1].y, sv4[kq][1].z, sv4[kq][1].w};
#pragma unroll
            for (int j = 0; j < 8; ++j) {
                float s = fmaf(aj[j], wa2, sl_i + sv[j]);
                s = __builtin_amdgcn_fmed3f(s, 0.2f * s, 86.5617f);
                float e = (aj[j] <= 1e-5f) ? 0.f : __builtin_amdgcn_exp2f(s);
                af[kq].b[j] = (__bf16)e;
            }
        }

        // (4) MFMAs
#pragma unroll
        for (int kq = 0; kq < 4; ++kq) {
            acc[0] = __builtin_amdgcn_mfma_f32_16x16x32_bf16(af[kq].b, B[kq][0].b, acc[0], 0, 0, 0);
            acc[1] = __builtin_amdgcn_mfma_f32_16x16x32_bf16(af[kq].b, B[kq][1].b, acc[1], 0, 0, 0);
            acc[2] = __builtin_amdgcn_mfma_f32_16x16x32_bf16(af[kq].b, B[kq][2].b, acc[2], 0, 0, 0);
            acc[3] = __builtin_amdgcn_mfma_f32_16x16x32_bf16(af[kq].b, B[kq][3].b, acc[3], 0, 0, 0);
            dacc   = __builtin_amdgcn_mfma_f32_16x16x32_bf16(af[kq].b, ones.b,   dacc,   0, 0, 0);
        }

        // (5) stage c+1 + nt copy write
        if (c + 1 < 4) {
            if (FUSE_ADJ) {
                nt_store4(out_adj + astg + (size_t)(c + 1) * MC, cur0);
                nt_store4(out_adj + astg + (size_t)(c + 1) * MC + 64, cur1);
            }
            *reinterpret_cast<float4*>(&abuf[(c + 1) & 1][sh][str][stc])      = cur0;
            *reinterpret_cast<float4*>(&abuf[(c + 1) & 1][sh][str][stc + 64]) = cur1;
        }
        __syncthreads();
        cur0 = nx0; cur1 = nx1;
    }

    // ---- cross-half combine (part overlays abuf; all LDS reads done) ----
    float (*part)[16][68] = reinterpret_cast<float (*)[16][68]>(&abuf[0][0][0][0]);
    if (mh == 1) {
#pragma unroll
        for (int bj = 0; bj < 4; ++bj)
#pragma unroll
            for (int q = 0; q < 4; ++q)
                part[h][g * 4 + q][bj * 16 + il] = acc[bj][q];
        if (il == 0) {
#pragma unroll
            for (int q = 0; q < 4; ++q) part[h][g * 4 + q][64] = dacc[q];
        }
    }
    __syncthreads();
    if (mh == 0) {
        const float* bb = bias + h * HDIM;
#pragma unroll
        for (int q = 0; q < 4; ++q) {
            const int row = g * 4 + q;
            const float den = dacc[q] + part[h][row][64];
            const float inv = 1.f / den;
            const size_t ob = ((size_t)(b * SEQ + i0 + row)) * CH + h * HDIM + il;
#pragma unroll
            for (int bj = 0; bj < 4; ++bj) {
                float m = acc[bj][q] + part[h][row][bj * 16 + il];
                float v = fmaf(m, inv, x[ob + bj * 16] + bb[bj * 16 + il]);
                v = fmaxf(v, 0.5f * v);
                __builtin_nontemporal_store(v, out + ob + bj * 16);
            }
        }
    }
}

// ---------------------------------------------------------------------------
// K4 (fallback): copy adj into output chunk 2
// ---------------------------------------------------------------------------
__global__ void adjcopy(const float* __restrict__ adj, float* __restrict__ dst, int n4) {
    int idx = blockIdx.x * blockDim.x + threadIdx.x;
    int stride = gridDim.x * blockDim.x;
    const float4* s = reinterpret_cast<const float4*>(adj);
    float4* d = reinterpret_cast<float4*>(dst);
    for (int i = idx; i < n4; i += stride) d[i] = s[i];
}

extern "C" void kernel_launch(void* const* d_in, const int* in_sizes, int n_in,
                              void* d_out, int out_size, void* d_ws, size_t ws_size,
                              hipStream_t stream) {
    const float* x    = (const float*)d_in[0];
    const float* adj  = (const float*)d_in[1];
    const float* Wp   = (const float*)d_in[2];
    const float* Ws   = (const float*)d_in[3];
    const float* bias = (const float*)d_in[4];
    float* out     = (float*)d_out;
    float* out_adj = out + (size_t)BATCH * SEQ * CH;

    const size_t nProj = (size_t)BATCH * SEQ * CH;
    const size_t nSc   = (size_t)BATCH * NHEADS * SEQ;
    const size_t need  = CH * CH * 2 + nProj * 2 + 2 * nSc * 4;
    const bool use_ws  = (ws_size >= need);
    char* scratch = use_ws ? (char*)d_ws : (char*)out_adj;
    unsigned short* WpT   = (unsigned short*)scratch;
    unsigned short* projT = (unsigned short*)(scratch + (size_t)CH * CH * 2);
    float*          sl    = (float*)(scratch + (size_t)CH * CH * 2 + nProj * 2);
    float*          sr    = sl + nSc;

    wpt_cast<<<dim3(8, 8), 256, 0, stream>>>(Wp, WpT);
    proj_fused<<<dim3(512), 256, 0, stream>>>(x, WpT, Ws, projT, sl, sr);
    if (use_ws) {
        attn13<true><<<dim3(512), 512, 0, stream>>>(
            x, adj, projT, sl, sr, Ws, bias, out, out_adj);
    } else {
        attn13<false><<<dim3(512), 512, 0, stream>>>(
            x, adj, projT, sl, sr, Ws, bias, out, out_adj);
        adjcopy<<<2048, 256, 0, stream>>>(adj, out_adj, (BATCH * SEQ * SEQ) / 4);
    }
}